// Round 1
// baseline (292.141 us; speedup 1.0000x reference)
//
#include <hip/hip_runtime.h>
#include <hip/hip_bf16.h>

#define LSP 4096   // L = H*W
#define NC  256    // C
#define NH  128    // C/2

typedef __attribute__((ext_vector_type(8))) short short8;
typedef __attribute__((ext_vector_type(4))) float f32x4;
typedef __attribute__((ext_vector_type(4))) unsigned int u32x4;
typedef __hip_bfloat16 bf16;

#define MFMA16(a,b,c) __builtin_amdgcn_mfma_f32_16x16x32_bf16((a),(b),(c),0,0,0)

typedef __attribute__((address_space(1))) const void gas_t;
typedef __attribute__((address_space(3))) void las_t;
#define GLDS16(g, l) __builtin_amdgcn_global_load_lds((gas_t*)(g), (las_t*)(l), 16, 0, 0)

static __device__ __forceinline__ unsigned short f2bf(float f) {
  bf16 h = __float2bfloat16(f);
  return __builtin_bit_cast(unsigned short, h);
}
static __device__ __forceinline__ unsigned int packbf2(float a, float b) {
  return (unsigned int)f2bf(a) | ((unsigned int)f2bf(b) << 16);
}

// ---------- weights fp32 -> bf16 (4 segments x 32768 elems) ----------
__global__ __launch_bounds__(256) void k_wconv(const float* __restrict__ a0,
    const float* __restrict__ a1, const float* __restrict__ a2,
    const float* __restrict__ a3, bf16* __restrict__ dst) {
  int i = blockIdx.x * 256 + threadIdx.x;
  int seg = i >> 15, off = i & 32767;
  const float* s = (seg == 0) ? a0 : (seg == 1) ? a1 : (seg == 2) ? a2 : a3;
  dst[i] = __float2bfloat16(s[off]);
}

// ---------- per (n,c): mean/unbiased-std -> sigmoid gate ----------
__global__ __launch_bounds__(256) void k_stats(const float* __restrict__ x,
    const float* __restrict__ cfc, float* __restrict__ gate) {
  int nc = blockIdx.x;   // n*C + c
  const float4* x4 = (const float4*)(x + (size_t)nc * LSP);
  float s = 0.f, q = 0.f;
  for (int i = threadIdx.x; i < LSP / 4; i += 256) {
    float4 v = x4[i];
    s += v.x + v.y + v.z + v.w;
    q += v.x * v.x + v.y * v.y + v.z * v.z + v.w * v.w;
  }
#pragma unroll
  for (int o = 32; o > 0; o >>= 1) { s += __shfl_xor(s, o); q += __shfl_xor(q, o); }
  __shared__ float rs[4], rq[4];
  int w = threadIdx.x >> 6;
  if ((threadIdx.x & 63) == 0) { rs[w] = s; rq[w] = q; }
  __syncthreads();
  if (threadIdx.x == 0) {
    float S = rs[0] + rs[1] + rs[2] + rs[3];
    float Q = rq[0] + rq[1] + rq[2] + rq[3];
    float mean = S / (float)LSP;
    float var = (Q - S * S / (float)LSP) / (float)(LSP - 1) + 1e-5f;
    float sd = sqrtf(var);
    int c = nc & (NC - 1);
    float z = mean * cfc[2 * c] + sd * cfc[2 * c + 1];
    gate[nc] = 1.f / (1.f + __expf(-z));
  }
}

// ---------- s_t[n][l][c] = bf16(x[n][c][l] * gate[n][c]) ----------
__global__ __launch_bounds__(256) void k_scale_t(const float* __restrict__ x,
    const float* __restrict__ gate, bf16* __restrict__ s_t) {
  int n = blockIdx.z;
  int c0 = blockIdx.y * 32;
  int l = blockIdx.x * 256 + threadIdx.x;
  unsigned int pk[16];
#pragma unroll
  for (int i = 0; i < 32; i += 2) {
    int c = c0 + i;
    float g0 = gate[n * NC + c];
    float g1 = gate[n * NC + c + 1];
    float v0 = x[((size_t)(n * NC + c)) * LSP + l] * g0;      // coalesced over l
    float v1 = x[((size_t)(n * NC + c + 1)) * LSP + l] * g1;
    pk[i >> 1] = packbf2(v0, v1);
  }
  u32x4* dst = (u32x4*)(s_t + ((size_t)n * LSP + l) * NC + c0);
#pragma unroll
  for (int k = 0; k < 4; ++k) dst[k] = ((const u32x4*)pk)[k];
}

// ---------- generic NT GEMM: D[M,N] = A[M,K] * B[N,K]^T + bias, bf16 out ----
// 64x64 tile, 4 waves; wave w: 16 cols, 64 rows. K multiple of 32.
__global__ __launch_bounds__(256) void k_gemm_nt(const bf16* __restrict__ A,
    const bf16* __restrict__ B, const float* __restrict__ bias, int bias_row,
    bf16* __restrict__ D, int Md, int Nd, int Kd, long sA, long sB, long sD) {
  int z = blockIdx.z;
  A += (size_t)z * sA; B += (size_t)z * sB; D += (size_t)z * sD;
  int tn = Nd >> 6;
  int m0 = (blockIdx.x / tn) * 64, n0 = (blockIdx.x % tn) * 64;
  int tid = threadIdx.x, w = tid >> 6, lane = tid & 63;
  int lo = lane & 15, g = lane >> 4;
  f32x4 zero = {0.f, 0.f, 0.f, 0.f};
  f32x4 acc[4];
#pragma unroll
  for (int i = 0; i < 4; ++i) acc[i] = zero;
  for (int kc = 0; kc < Kd; kc += 32) {
    short8 bfr = *(const short8*)(B + (size_t)(n0 + w * 16 + lo) * Kd + kc + g * 8);
#pragma unroll
    for (int i = 0; i < 4; ++i) {
      short8 afr = *(const short8*)(A + (size_t)(m0 + 16 * i + lo) * Kd + kc + g * 8);
      acc[i] = MFMA16(afr, bfr, acc[i]);
    }
  }
  int col = n0 + w * 16 + lo;
#pragma unroll
  for (int i = 0; i < 4; ++i)
#pragma unroll
    for (int r = 0; r < 4; ++r) {
      int row = m0 + 16 * i + g * 4 + r;
      float bv = bias_row ? bias[row] : bias[col];
      D[(size_t)row * Nd + col] = __float2bfloat16(acc[i][r] + bv);
    }
}

// ---------- flash attention: O[l][d] = softmax_j(Q Kt) V, no scale ----------
// Q=theta_t[L][128], K=phi_t[L][128], V from gT[128][L]. 4 waves x 16 q rows.
__global__ __launch_bounds__(256) void k_attn(const bf16* __restrict__ th_t,
    const bf16* __restrict__ ph_t, const bf16* __restrict__ gT,
    bf16* __restrict__ O_t) {
  __shared__ bf16 Kl[2][32 * 128];   // [j][k], 16B-chunk XOR-swizzled by (j&7)
  __shared__ bf16 Vl[2][128 * 32];   // [d][j], 16B-chunk XOR-swizzled by (d&3)
  __shared__ bf16 Pl[4][16 * 40];    // per-wave P[q][j], row stride 40 elems (80B)

  const int n = blockIdx.z;
  const int tid = threadIdx.x;
  const int w = tid >> 6;
  const int lane = tid & 63;
  const int lo = lane & 15;
  const int g = lane >> 4;

  const bf16* ph = ph_t + (size_t)n * LSP * NH;
  const bf16* gv = gT + (size_t)n * NH * LSP;
  const bf16* th = th_t + ((size_t)n * LSP + blockIdx.x * 64 + w * 16) * NH;

  // Q B-frags: B[k][q] = Q[q][k]; lane reads Q row lo, k = kc*32 + g*8 .. +7
  short8 qf[4];
#pragma unroll
  for (int kc = 0; kc < 4; ++kc)
    qf[kc] = *(const short8*)(th + lo * NH + kc * 32 + g * 8);

  f32x4 zero = {0.f, 0.f, 0.f, 0.f};
  f32x4 acc[8];
#pragma unroll
  for (int dc = 0; dc < 8; ++dc) acc[dc] = zero;
  float m = -1e30f, lsum = 0.f;

  auto stage = [&](int j0, int buf) {
#pragma unroll
    for (int i = 0; i < 2; ++i) {
      int ci = i * 256 + tid;                 // 512 x 16B chunks each
      int j = ci >> 4, cc = ci & 15;          // K tile: row j (256B), chunk cc
      GLDS16(ph + (size_t)(j0 + j) * NH + ((cc ^ (j & 7)) * 8),
             (char*)&Kl[buf][0] + ci * 16);
      int d = ci >> 2, c2 = ci & 3;           // V tile: row d (64B), chunk c2
      GLDS16(gv + (size_t)d * LSP + j0 + ((c2 ^ (d & 3)) * 8),
             (char*)&Vl[buf][0] + ci * 16);
    }
  };

  stage(0, 0);
  __syncthreads();

  for (int t = 0; t < LSP / 32; ++t) {
    int cur = t & 1;
    if (t + 1 < LSP / 32) stage((t + 1) * 32, cur ^ 1);  // issue early, wait at barrier

    const char* Kb = (const char*)&Kl[cur][0];
    const char* Vb = (const char*)&Vl[cur][0];

    // S^T tiles: ST[j][q] = sum_k K[j][k] Q[q][k]  (D: row=j_local, col=q)
    f32x4 st0 = zero, st1 = zero;
#pragma unroll
    for (int kc = 0; kc < 4; ++kc) {
      int kb = kc * 64 + g * 16;
      short8 ka = *(const short8*)(Kb + lo * 256 + (kb ^ ((lo & 7) << 4)));
      st0 = MFMA16(ka, qf[kc], st0);
      int j1 = lo + 16;
      short8 ka2 = *(const short8*)(Kb + j1 * 256 + (kb ^ ((j1 & 7) << 4)));
      st1 = MFMA16(ka2, qf[kc], st1);
    }

    // online softmax for q = lo (state replicated across the 4 lane-groups)
    float tm = fmaxf(fmaxf(fmaxf(st0[0], st0[1]), fmaxf(st0[2], st0[3])),
                     fmaxf(fmaxf(st1[0], st1[1]), fmaxf(st1[2], st1[3])));
    tm = fmaxf(tm, __shfl_xor(tm, 16));
    tm = fmaxf(tm, __shfl_xor(tm, 32));
    float nm = fmaxf(m, tm);
    float alpha = __expf(m - nm);
    float p0[4], p1[4], ps = 0.f;
#pragma unroll
    for (int r = 0; r < 4; ++r) {
      p0[r] = __expf(st0[r] - nm); ps += p0[r];
      p1[r] = __expf(st1[r] - nm); ps += p1[r];
    }
    ps += __shfl_xor(ps, 16);
    ps += __shfl_xor(ps, 32);
    lsum = lsum * alpha + ps;
    m = nm;

    // write P[q=lo][j] (j = g*4+r and 16+g*4+r), packed u32 pairs
    unsigned int* pw = (unsigned int*)((char*)&Pl[w][0] + lo * 80);
    pw[g * 2 + 0] = packbf2(p0[0], p0[1]);
    pw[g * 2 + 1] = packbf2(p0[2], p0[3]);
    pw[8 + g * 2 + 0] = packbf2(p1[0], p1[1]);
    pw[8 + g * 2 + 1] = packbf2(p1[2], p1[3]);

    // rescale O rows (O-layout q = g*4+r; alpha lives at lane q)
    float al0 = __shfl(alpha, g * 4 + 0);
    float al1 = __shfl(alpha, g * 4 + 1);
    float al2 = __shfl(alpha, g * 4 + 2);
    float al3 = __shfl(alpha, g * 4 + 3);
#pragma unroll
    for (int dc = 0; dc < 8; ++dc) {
      acc[dc][0] *= al0; acc[dc][1] *= al1; acc[dc][2] *= al2; acc[dc][3] *= al3;
    }

    asm volatile("" ::: "memory");  // order P ds_write before ds_read (TBAA guard)
    // PV: A-frag = P[lo][g*8..+7]; B-frag = V[j][d] from Vl row d
    short8 pa = *(const short8*)((const char*)&Pl[w][0] + lo * 80 + g * 16);
#pragma unroll
    for (int dc = 0; dc < 8; ++dc) {
      int d = dc * 16 + lo;
      short8 vb = *(const short8*)(Vb + d * 64 + ((g * 16) ^ ((d & 3) << 4)));
      acc[dc] = MFMA16(pa, vb, acc[dc]);
    }
    __syncthreads();  // tile t+1 ready; buf cur free for t+2
  }

  float li0 = 1.f / __shfl(lsum, g * 4 + 0);
  float li1 = 1.f / __shfl(lsum, g * 4 + 1);
  float li2 = 1.f / __shfl(lsum, g * 4 + 2);
  float li3 = 1.f / __shfl(lsum, g * 4 + 3);
  bf16* op = O_t + ((size_t)n * LSP + blockIdx.x * 64 + w * 16) * NH;
#pragma unroll
  for (int dc = 0; dc < 8; ++dc) {
    op[(g * 4 + 0) * NH + dc * 16 + lo] = __float2bfloat16(acc[dc][0] * li0);
    op[(g * 4 + 1) * NH + dc * 16 + lo] = __float2bfloat16(acc[dc][1] * li1);
    op[(g * 4 + 2) * NH + dc * 16 + lo] = __float2bfloat16(acc[dc][2] * li2);
    op[(g * 4 + 3) * NH + dc * 16 + lo] = __float2bfloat16(acc[dc][3] * li3);
  }
}

// ---------- out[c][l] = x*gate + out_b[c] + sum_ch out_w[c][ch] * O_t[l][ch] --
__global__ __launch_bounds__(256) void k_final(const bf16* __restrict__ Wo,
    const bf16* __restrict__ O_t, const float* __restrict__ x,
    const float* __restrict__ gate, const float* __restrict__ ob,
    float* __restrict__ out) {
  int n = blockIdx.z;
  int m0 = (blockIdx.x >> 6) * 64, n0 = (blockIdx.x & 63) * 64;
  int tid = threadIdx.x, w = tid >> 6, lane = tid & 63;
  int lo = lane & 15, g = lane >> 4;
  const bf16* Bp = O_t + (size_t)n * LSP * NH;
  f32x4 zero = {0.f, 0.f, 0.f, 0.f};
  f32x4 acc[4];
#pragma unroll
  for (int i = 0; i < 4; ++i) acc[i] = zero;
  int col = n0 + w * 16 + lo;
#pragma unroll
  for (int kc = 0; kc < 4; ++kc) {
    short8 bfr = *(const short8*)(Bp + (size_t)col * NH + kc * 32 + g * 8);
#pragma unroll
    for (int i = 0; i < 4; ++i) {
      short8 afr = *(const short8*)(Wo + (size_t)(m0 + 16 * i + lo) * NH + kc * 32 + g * 8);
      acc[i] = MFMA16(afr, bfr, acc[i]);
    }
  }
#pragma unroll
  for (int i = 0; i < 4; ++i)
#pragma unroll
    for (int r = 0; r < 4; ++r) {
      int c = m0 + 16 * i + g * 4 + r;
      size_t xo = ((size_t)(n * NC + c)) * LSP + col;
      out[xo] = acc[i][r] + ob[c] + x[xo] * gate[n * NC + c];
    }
}

extern "C" void kernel_launch(void* const* d_in, const int* in_sizes, int n_in,
                              void* d_out, int out_size, void* d_ws, size_t ws_size,
                              hipStream_t stream) {
  const float* x       = (const float*)d_in[0];
  const float* cfc     = (const float*)d_in[1];
  const float* theta_w = (const float*)d_in[2];
  const float* theta_b = (const float*)d_in[3];
  const float* phi_w   = (const float*)d_in[4];
  const float* phi_b   = (const float*)d_in[5];
  const float* g_w     = (const float*)d_in[6];
  const float* g_b     = (const float*)d_in[7];
  const float* out_w   = (const float*)d_in[8];
  const float* out_b   = (const float*)d_in[9];
  float* out = (float*)d_out;

  char* p = (char*)d_ws;
  auto alloc = [&](size_t bytes) { char* r = p; p += (bytes + 255) & ~(size_t)255; return r; };
  float* gate = (float*)alloc(4 * NC * sizeof(float));
  bf16* s_t   = (bf16*)alloc((size_t)4 * LSP * NC * 2);   // [n][l][c]
  bf16* th_t  = (bf16*)alloc((size_t)4 * LSP * NH * 2);   // [n][l][o]
  bf16* ph_t  = (bf16*)alloc((size_t)4 * LSP * NH * 2);   // [n][l][o]
  bf16* gTb   = (bf16*)alloc((size_t)4 * NH * LSP * 2);   // [n][o][l]
  bf16* O_t   = (bf16*)alloc((size_t)4 * LSP * NH * 2);   // [n][l][d]
  bf16* wbf   = (bf16*)alloc((size_t)4 * 32768 * 2);      // thW|phW|gW|outW

  k_wconv<<<512, 256, 0, stream>>>(theta_w, phi_w, g_w, out_w, wbf);
  k_stats<<<4 * NC, 256, 0, stream>>>(x, cfc, gate);
  k_scale_t<<<dim3(16, 8, 4), 256, 0, stream>>>(x, gate, s_t);

  // theta_t[l][o], phi_t[l][o]: A = s_t[L,C], B = W[Ch,C]; col-bias
  k_gemm_nt<<<dim3(128, 1, 4), 256, 0, stream>>>(s_t, wbf, theta_b, 0, th_t,
      LSP, NH, NC, (long)LSP * NC, 0, (long)LSP * NH);
  k_gemm_nt<<<dim3(128, 1, 4), 256, 0, stream>>>(s_t, wbf + 32768, phi_b, 0, ph_t,
      LSP, NH, NC, (long)LSP * NC, 0, (long)LSP * NH);
  // gT[o][l]: A = g_w[Ch,C], B = s_t[L,C]; row-bias
  k_gemm_nt<<<dim3(128, 1, 4), 256, 0, stream>>>(wbf + 65536, s_t, g_b, 1, gTb,
      NH, LSP, NC, 0, (long)LSP * NC, (long)NH * LSP);

  k_attn<<<dim3(64, 1, 4), 256, 0, stream>>>(th_t, ph_t, gTb, O_t);
  k_final<<<dim3(256, 1, 4), 256, 0, stream>>>(wbf + 98304, O_t, x, gate, out_b, out);
}

// Round 2
// 198.819 us; speedup vs baseline: 1.4694x; 1.4694x over previous
//
#include <hip/hip_runtime.h>
#include <hip/hip_bf16.h>

#define LSP 4096   // L = H*W
#define NC  256    // C
#define NH  128    // C/2
#define KB  64     // kv tile
#define SPLIT 4    // kv split factor
#define NTILE ((LSP / SPLIT) / KB)   // 16

typedef __attribute__((ext_vector_type(8))) short short8;
typedef __attribute__((ext_vector_type(4))) float f32x4;
typedef __attribute__((ext_vector_type(4))) unsigned int u32x4;
typedef __attribute__((ext_vector_type(2))) unsigned int u32x2;
typedef __attribute__((ext_vector_type(4))) unsigned short u16x4;
typedef __hip_bfloat16 bf16;

#define MFMA16(a,b,c) __builtin_amdgcn_mfma_f32_16x16x32_bf16((a),(b),(c),0,0,0)

typedef __attribute__((address_space(1))) const void gas_t;
typedef __attribute__((address_space(3))) void las_t;
#define GLDS16(g, l) __builtin_amdgcn_global_load_lds((gas_t*)(g), (las_t*)(l), 16, 0, 0)

static __device__ __forceinline__ unsigned short f2bf(float f) {
  bf16 h = __float2bfloat16(f);
  return __builtin_bit_cast(unsigned short, h);
}
static __device__ __forceinline__ unsigned int packbf2(float a, float b) {
  return (unsigned int)f2bf(a) | ((unsigned int)f2bf(b) << 16);
}
static __device__ __forceinline__ float bf2f(unsigned short u) {
  return __builtin_bit_cast(float, (unsigned int)u << 16);
}

// ---------- weights fp32 -> bf16 (4 segments x 32768) + concat theta|phi bias
__global__ __launch_bounds__(256) void k_wconv(const float* __restrict__ a0,
    const float* __restrict__ a1, const float* __restrict__ a2,
    const float* __restrict__ a3, const float* __restrict__ tb,
    const float* __restrict__ pb, bf16* __restrict__ dst, float* __restrict__ bcat) {
  int i = blockIdx.x * 256 + threadIdx.x;
  int seg = i >> 15, off = i & 32767;
  const float* s = (seg == 0) ? a0 : (seg == 1) ? a1 : (seg == 2) ? a2 : a3;
  dst[i] = __float2bfloat16(s[off]);
  if (blockIdx.x == 0)
    bcat[threadIdx.x] = threadIdx.x < 128 ? tb[threadIdx.x] : pb[threadIdx.x - 128];
}

// ---------- per (n,c): mean/unbiased-std -> sigmoid gate ----------
__global__ __launch_bounds__(256) void k_stats(const float* __restrict__ x,
    const float* __restrict__ cfc, float* __restrict__ gate) {
  int nc = blockIdx.x;   // n*C + c
  const float4* x4 = (const float4*)(x + (size_t)nc * LSP);
  float s = 0.f, q = 0.f;
  for (int i = threadIdx.x; i < LSP / 4; i += 256) {
    float4 v = x4[i];
    s += v.x + v.y + v.z + v.w;
    q += v.x * v.x + v.y * v.y + v.z * v.z + v.w * v.w;
  }
#pragma unroll
  for (int o = 32; o > 0; o >>= 1) { s += __shfl_xor(s, o); q += __shfl_xor(q, o); }
  __shared__ float rs[4], rq[4];
  int w = threadIdx.x >> 6;
  if ((threadIdx.x & 63) == 0) { rs[w] = s; rq[w] = q; }
  __syncthreads();
  if (threadIdx.x == 0) {
    float S = rs[0] + rs[1] + rs[2] + rs[3];
    float Q = rq[0] + rq[1] + rq[2] + rq[3];
    float mean = S / (float)LSP;
    float var = (Q - S * S / (float)LSP) / (float)(LSP - 1) + 1e-5f;
    float sd = sqrtf(var);
    int c = nc & (NC - 1);
    float z = mean * cfc[2 * c] + sd * cfc[2 * c + 1];
    gate[nc] = 1.f / (1.f + __expf(-z));
  }
}

// ---------- s_t[n][l][c] = bf16(x[n][c][l] * gate[n][c]) ----------
__global__ __launch_bounds__(256) void k_scale_t(const float* __restrict__ x,
    const float* __restrict__ gate, bf16* __restrict__ s_t) {
  int n = blockIdx.z;
  int c0 = blockIdx.y * 32;
  int l = blockIdx.x * 256 + threadIdx.x;
  unsigned int pk[16];
#pragma unroll
  for (int i = 0; i < 32; i += 2) {
    int c = c0 + i;
    float g0 = gate[n * NC + c];
    float g1 = gate[n * NC + c + 1];
    float v0 = x[((size_t)(n * NC + c)) * LSP + l] * g0;
    float v1 = x[((size_t)(n * NC + c + 1)) * LSP + l] * g1;
    pk[i >> 1] = packbf2(v0, v1);
  }
  u32x4* dst = (u32x4*)(s_t + ((size_t)n * LSP + l) * NC + c0);
#pragma unroll
  for (int k = 0; k < 4; ++k) dst[k] = ((const u32x4*)pk)[k];
}

// ---------- generic NT GEMM: D[M,N] = A[M,K] * B[N,K]^T + bias, bf16 out ----
__global__ __launch_bounds__(256) void k_gemm_nt(const bf16* __restrict__ A,
    const bf16* __restrict__ B, const float* __restrict__ bias, int bias_row,
    bf16* __restrict__ D, int Md, int Nd, int Kd, long sA, long sB, long sD) {
  int z = blockIdx.z;
  A += (size_t)z * sA; B += (size_t)z * sB; D += (size_t)z * sD;
  int tn = Nd >> 6;
  int m0 = (blockIdx.x / tn) * 64, n0 = (blockIdx.x % tn) * 64;
  int tid = threadIdx.x, w = tid >> 6, lane = tid & 63;
  int lo = lane & 15, g = lane >> 4;
  f32x4 zero = {0.f, 0.f, 0.f, 0.f};
  f32x4 acc[4];
#pragma unroll
  for (int i = 0; i < 4; ++i) acc[i] = zero;
  for (int kc = 0; kc < Kd; kc += 32) {
    short8 bfr = *(const short8*)(B + (size_t)(n0 + w * 16 + lo) * Kd + kc + g * 8);
#pragma unroll
    for (int i = 0; i < 4; ++i) {
      short8 afr = *(const short8*)(A + (size_t)(m0 + 16 * i + lo) * Kd + kc + g * 8);
      acc[i] = MFMA16(afr, bfr, acc[i]);
    }
  }
  int col = n0 + w * 16 + lo;
#pragma unroll
  for (int i = 0; i < 4; ++i)
#pragma unroll
    for (int r = 0; r < 4; ++r) {
      int row = m0 + 16 * i + g * 4 + r;
      float bv = bias_row ? bias[row] : bias[col];
      D[(size_t)row * Nd + col] = __float2bfloat16(acc[i][r] + bv);
    }
}

// ---------- flash attention with kv-split ----------
// Q = thph[n][l][0:128], K = thph[n][l][128:256], V from gT[n][128][L].
// 4 waves x 32 q-rows = 128 q/block; KV tile 64; SPLIT-way j partition.
// Outputs unnormalized O partial (bf16) + (m, lsum) per row.
__global__ __launch_bounds__(256, 2) void k_attn(const bf16* __restrict__ thph,
    const bf16* __restrict__ gT, bf16* __restrict__ Opart, float* __restrict__ ml) {
  __shared__ bf16 Kl[2][KB * NH];    // [j][k] 256B rows, chunk ^= (j&7)      32 KB
  __shared__ bf16 Vl[2][NH * KB];    // [d][j] 128B rows, chunk ^= (d&7)      32 KB
  __shared__ bf16 Pl[4][32 * KB];    // per-wave [row][j] 128B rows, ^=(row&7) 16 KB

  const int n = blockIdx.z, sp = blockIdx.y;
  const int tid = threadIdx.x, w = tid >> 6, lane = tid & 63;
  const int lo = lane & 15, g = lane >> 4;
  const int swz = (lo & 7) << 4;

  const bf16* thn = thph + (size_t)n * LSP * 256;
  const bf16* gv  = gT + (size_t)n * NH * LSP;
  const int q0 = blockIdx.x * 128 + w * 32;
  const int j0base = sp * (LSP / SPLIT);

  // Q B-frags: lane reads Q row (q0+qs*16+lo), k = kc*32 + g*8 ..+7 (theta cols)
  short8 qf[2][4];
#pragma unroll
  for (int qs = 0; qs < 2; ++qs)
#pragma unroll
    for (int kc = 0; kc < 4; ++kc)
      qf[qs][kc] = *(const short8*)(thn + (size_t)(q0 + qs * 16 + lo) * 256 + kc * 32 + g * 8);

  // per-thread staging offsets (source pre-swizzled; LDS dest linear, rule 21)
  size_t koff[4], voff[4];
  int ldso[4];
#pragma unroll
  for (int i = 0; i < 4; ++i) {
    int ci = i * 256 + tid;
    int kj = ci >> 4, kcc = ci & 15;
    koff[i] = (size_t)kj * 256 + 128 + ((kcc ^ (kj & 7)) * 8);
    int vd = ci >> 3, vc2 = ci & 7;
    voff[i] = (size_t)vd * LSP + ((vc2 ^ (vd & 7)) * 8);
    ldso[i] = ci * 16;
  }

#define STAGE(JT, BUF) do { \
    const bf16* ksrc = thn + (size_t)(j0base + (JT) * KB) * 256; \
    const bf16* vsrc = gv + (j0base + (JT) * KB); \
    char* kdst = (char*)&Kl[BUF][0]; \
    char* vdst = (char*)&Vl[BUF][0]; \
    _Pragma("unroll") \
    for (int i = 0; i < 4; ++i) { \
      GLDS16(ksrc + koff[i], kdst + ldso[i]); \
      GLDS16(vsrc + voff[i], vdst + ldso[i]); \
    } } while (0)

  f32x4 zero = {0.f, 0.f, 0.f, 0.f};
  f32x4 acc[2][8];
#pragma unroll
  for (int qs = 0; qs < 2; ++qs)
#pragma unroll
    for (int dc = 0; dc < 8; ++dc) acc[qs][dc] = zero;
  float mv[2] = {-1e30f, -1e30f};
  float ls[2] = {0.f, 0.f};

  STAGE(0, 0);
  __syncthreads();

  char* pwb = (char*)&Pl[w][0];

  for (int t = 0; t < NTILE; ++t) {
    int cur = t & 1;
    if (t + 1 < NTILE) STAGE(t + 1, cur ^ 1);  // issue early; drained at barrier
    const char* Kb = (const char*)&Kl[cur][0];
    const char* Vb = (const char*)&Vl[cur][0];

    // S^T: ST[j][q] = sum_k K[j][k] Q[q][k]; K-frag shared across both q-sets
    f32x4 st[2][4];
#pragma unroll
    for (int qs = 0; qs < 2; ++qs)
#pragma unroll
      for (int jt = 0; jt < 4; ++jt) st[qs][jt] = zero;
#pragma unroll
    for (int kc = 0; kc < 4; ++kc) {
      int kb = (kc * 64 + g * 16) ^ swz;
#pragma unroll
      for (int jt = 0; jt < 4; ++jt) {
        short8 ka = *(const short8*)(Kb + (jt * 16 + lo) * 256 + kb);
        st[0][jt] = MFMA16(ka, qf[0][kc], st[0][jt]);
        st[1][jt] = MFMA16(ka, qf[1][kc], st[1][jt]);
      }
    }

    // tile max per q-set (q = lo, replicated over lane-groups)
    float tm[2];
#pragma unroll
    for (int qs = 0; qs < 2; ++qs) {
      float t0 = fmaxf(fmaxf(st[qs][0][0], st[qs][0][1]), fmaxf(st[qs][0][2], st[qs][0][3]));
      float t1 = fmaxf(fmaxf(st[qs][1][0], st[qs][1][1]), fmaxf(st[qs][1][2], st[qs][1][3]));
      float t2 = fmaxf(fmaxf(st[qs][2][0], st[qs][2][1]), fmaxf(st[qs][2][2], st[qs][2][3]));
      float t3 = fmaxf(fmaxf(st[qs][3][0], st[qs][3][1]), fmaxf(st[qs][3][2], st[qs][3][3]));
      float tq = fmaxf(fmaxf(t0, t1), fmaxf(t2, t3));
      tq = fmaxf(tq, __shfl_xor(tq, 16));
      tq = fmaxf(tq, __shfl_xor(tq, 32));
      tm[qs] = tq;
    }

    // defer-max: rescale only when the running max grows past threshold
    int need = (tm[0] > mv[0] + 8.f) || (tm[1] > mv[1] + 8.f);
    if (__any(need)) {
      float nm0 = fmaxf(mv[0], tm[0]), nm1 = fmaxf(mv[1], tm[1]);
      float a0 = __expf(mv[0] - nm0), a1 = __expf(mv[1] - nm1);
      mv[0] = nm0; mv[1] = nm1; ls[0] *= a0; ls[1] *= a1;
#pragma unroll
      for (int r = 0; r < 4; ++r) {
        float b0 = __shfl(a0, g * 4 + r);
        float b1 = __shfl(a1, g * 4 + r);
#pragma unroll
        for (int dc = 0; dc < 8; ++dc) { acc[0][dc][r] *= b0; acc[1][dc][r] *= b1; }
      }
    }

    // P = exp(S - m), packed bf16 into swizzled per-wave LDS rows
#pragma unroll
    for (int qs = 0; qs < 2; ++qs) {
      float mm = mv[qs];
      float psum = 0.f;
      int rowb = (qs * 16 + lo) * 128;
#pragma unroll
      for (int jt = 0; jt < 4; ++jt) {
        float e0 = __expf(st[qs][jt][0] - mm);
        float e1 = __expf(st[qs][jt][1] - mm);
        float e2 = __expf(st[qs][jt][2] - mm);
        float e3 = __expf(st[qs][jt][3] - mm);
        psum += (e0 + e1) + (e2 + e3);
        u32x2 pk;
        pk.x = packbf2(e0, e1);
        pk.y = packbf2(e2, e3);
        *(u32x2*)(pwb + rowb + ((jt * 32 + g * 8) ^ swz)) = pk;
      }
      psum += __shfl_xor(psum, 16);
      psum += __shfl_xor(psum, 32);
      ls[qs] += psum;
    }

    asm volatile("" ::: "memory");  // order P ds_writes before ds_reads
    // PV: V-frag shared across both q-sets
#pragma unroll
    for (int kc2 = 0; kc2 < 2; ++kc2) {
      int kbb = kc2 * 64 + g * 16;
      short8 pa0 = *(const short8*)(pwb + lo * 128 + (kbb ^ swz));
      short8 pa1 = *(const short8*)(pwb + (16 + lo) * 128 + (kbb ^ swz));
#pragma unroll
      for (int dc = 0; dc < 8; ++dc) {
        int d = dc * 16 + lo;
        short8 vb = *(const short8*)(Vb + d * 128 + (kbb ^ ((d & 7) << 4)));
        acc[0][dc] = MFMA16(pa0, vb, acc[0][dc]);
        acc[1][dc] = MFMA16(pa1, vb, acc[1][dc]);
      }
    }
    __syncthreads();  // prefetch drained; both buffers consistent
  }

  // epilogue: unnormalized partial O (bf16) + (m, lsum)
  bf16* opb = Opart + ((size_t)(sp * 4 + n) * LSP + q0) * NH;
#pragma unroll
  for (int qs = 0; qs < 2; ++qs)
#pragma unroll
    for (int dc = 0; dc < 8; ++dc)
#pragma unroll
      for (int r = 0; r < 4; ++r)
        opb[(size_t)(qs * 16 + g * 4 + r) * NH + dc * 16 + lo] =
            __float2bfloat16(acc[qs][dc][r]);
  if (g == 0) {
    float2* mlp = (float2*)ml + (size_t)(sp * 4 + n) * LSP + q0;
    mlp[lo] = make_float2(mv[0], ls[0]);
    mlp[16 + lo] = make_float2(mv[1], ls[1]);
  }
#undef STAGE
}

// ---------- combine kv-split partials -> O_t[n][l][d] bf16 ----------
__global__ __launch_bounds__(256) void k_comb(const bf16* __restrict__ Opart,
    const float* __restrict__ ml, bf16* __restrict__ O_t) {
  int t = blockIdx.x * 256 + threadIdx.x;   // 524288 threads, 4 d's each
  int nl = t >> 5, d0 = (t & 31) * 4;
  float2 m4[SPLIT];
  float mx = -1e30f;
#pragma unroll
  for (int s = 0; s < SPLIT; ++s) {
    m4[s] = ((const float2*)ml)[(size_t)s * (4 * LSP) + nl];
    mx = fmaxf(mx, m4[s].x);
  }
  float den = 0.f, ws[SPLIT];
#pragma unroll
  for (int s = 0; s < SPLIT; ++s) {
    ws[s] = __expf(m4[s].x - mx);
    den += m4[s].y * ws[s];
  }
  float inv = 1.f / den;
  float o0 = 0.f, o1 = 0.f, o2 = 0.f, o3 = 0.f;
#pragma unroll
  for (int s = 0; s < SPLIT; ++s) {
    u16x4 v = *(const u16x4*)(Opart + ((size_t)s * (4 * LSP) + nl) * NH + d0);
    float sc = ws[s] * inv;
    o0 += bf2f(v.x) * sc; o1 += bf2f(v.y) * sc;
    o2 += bf2f(v.z) * sc; o3 += bf2f(v.w) * sc;
  }
  u32x2 pk;
  pk.x = packbf2(o0, o1);
  pk.y = packbf2(o2, o3);
  *(u32x2*)(O_t + (size_t)nl * NH + d0) = pk;
}

// ---------- out[c][l] = x*gate + out_b[c] + sum_ch out_w[c][ch] * O_t[l][ch] --
__global__ __launch_bounds__(256) void k_final(const bf16* __restrict__ Wo,
    const bf16* __restrict__ O_t, const float* __restrict__ x,
    const float* __restrict__ gate, const float* __restrict__ ob,
    float* __restrict__ out) {
  int n = blockIdx.z;
  int m0 = (blockIdx.x >> 6) * 64, n0 = (blockIdx.x & 63) * 64;
  int tid = threadIdx.x, w = tid >> 6, lane = tid & 63;
  int lo = lane & 15, g = lane >> 4;
  const bf16* Bp = O_t + (size_t)n * LSP * NH;
  f32x4 zero = {0.f, 0.f, 0.f, 0.f};
  f32x4 acc[4];
#pragma unroll
  for (int i = 0; i < 4; ++i) acc[i] = zero;
  int col = n0 + w * 16 + lo;
#pragma unroll
  for (int kc = 0; kc < 4; ++kc) {
    short8 bfr = *(const short8*)(Bp + (size_t)col * NH + kc * 32 + g * 8);
#pragma unroll
    for (int i = 0; i < 4; ++i) {
      short8 afr = *(const short8*)(Wo + (size_t)(m0 + 16 * i + lo) * NH + kc * 32 + g * 8);
      acc[i] = MFMA16(afr, bfr, acc[i]);
    }
  }
#pragma unroll
  for (int i = 0; i < 4; ++i)
#pragma unroll
    for (int r = 0; r < 4; ++r) {
      int c = m0 + 16 * i + g * 4 + r;
      size_t xo = ((size_t)(n * NC + c)) * LSP + col;
      out[xo] = acc[i][r] + ob[c] + x[xo] * gate[n * NC + c];
    }
}

extern "C" void kernel_launch(void* const* d_in, const int* in_sizes, int n_in,
                              void* d_out, int out_size, void* d_ws, size_t ws_size,
                              hipStream_t stream) {
  const float* x       = (const float*)d_in[0];
  const float* cfc     = (const float*)d_in[1];
  const float* theta_w = (const float*)d_in[2];
  const float* theta_b = (const float*)d_in[3];
  const float* phi_w   = (const float*)d_in[4];
  const float* phi_b   = (const float*)d_in[5];
  const float* g_w     = (const float*)d_in[6];
  const float* g_b     = (const float*)d_in[7];
  const float* out_w   = (const float*)d_in[8];
  const float* out_b   = (const float*)d_in[9];
  float* out = (float*)d_out;

  char* p = (char*)d_ws;
  auto alloc = [&](size_t bytes) { char* r = p; p += (bytes + 255) & ~(size_t)255; return r; };
  float* gate  = (float*)alloc(4 * NC * sizeof(float));
  bf16* s_t    = (bf16*)alloc((size_t)4 * LSP * NC * 2);          // [n][l][c]
  bf16* thph   = (bf16*)alloc((size_t)4 * LSP * 256 * 2);         // [n][l][th|ph]
  bf16* gTb    = (bf16*)alloc((size_t)4 * NH * LSP * 2);          // [n][o][l]
  bf16* O_t    = (bf16*)alloc((size_t)4 * LSP * NH * 2);          // [n][l][d]
  bf16* wbf    = (bf16*)alloc((size_t)4 * 32768 * 2);             // thW|phW|gW|outW
  float* bcat  = (float*)alloc(256 * sizeof(float));              // theta_b|phi_b
  bf16* Opart  = (bf16*)alloc((size_t)SPLIT * 4 * LSP * NH * 2);  // [s][n][l][d]
  float* ml    = (float*)alloc((size_t)SPLIT * 4 * LSP * 2 * 4);  // [s][n][l][2]

  k_wconv<<<512, 256, 0, stream>>>(theta_w, phi_w, g_w, out_w, theta_b, phi_b, wbf, bcat);
  k_stats<<<4 * NC, 256, 0, stream>>>(x, cfc, gate);
  k_scale_t<<<dim3(16, 8, 4), 256, 0, stream>>>(x, gate, s_t);

  // fused theta|phi: A = s_t[L,C], B = [thW;phW][256,C]; col-bias = bcat
  k_gemm_nt<<<dim3(256, 1, 4), 256, 0, stream>>>(s_t, wbf, bcat, 0, thph,
      LSP, 256, NC, (long)LSP * NC, 0, (long)LSP * 256);
  // gT[o][l]: A = g_w[Ch,C], B = s_t[L,C]; row-bias
  k_gemm_nt<<<dim3(128, 1, 4), 256, 0, stream>>>(wbf + 65536, s_t, g_b, 1, gTb,
      NH, LSP, NC, 0, (long)LSP * NC, (long)NH * LSP);

  k_attn<<<dim3(LSP / 128, SPLIT, 4), 256, 0, stream>>>(thph, gTb, Opart, ml);
  k_comb<<<(4 * LSP * 32) / 256, 256, 0, stream>>>(Opart, ml, O_t);
  k_final<<<dim3(256, 1, 4), 256, 0, stream>>>(wbf + 98304, O_t, x, gate, out_b, out);
}